// Round 2
// baseline (168.969 us; speedup 1.0000x reference)
//
#include <hip/hip_runtime.h>
#include <hip/hip_bf16.h>

using short8  = __attribute__((ext_vector_type(8))) short;
using floatx4 = __attribute__((ext_vector_type(4))) float;

#define GPTR(p) ((const __attribute__((address_space(1))) void*)(p))
#define LPTR(p) ((__attribute__((address_space(3))) void*)(p))

// ---------------------------------------------------------------------------
// Stage 1 (prep): grid = 64 + 8192 blocks.
//  blocks 0..63   : Wc[1024,1024] bf16 = Wi[1024,256] * Ws[256,1024]  (fp32 in)
//  blocks 64..8255: xb bf16 image copy of x fp32 (straight convert, coalesced)
// Wc block: BM=BN=128, BK=64 over K=256. A=Wi row-major (B^T-form already).
// B operand Ws is [s,k] (K-major) -> stage coalesced into Bs2[s][col] and do
// strided ds_read_u16 fragment builds (tiny kernel; conflict cost irrelevant).
// ---------------------------------------------------------------------------
__global__ __launch_bounds__(256) void prep_kernel(const float* __restrict__ x,
                                                   const float* __restrict__ w_sample,
                                                   const float* __restrict__ w_init,
                                                   __hip_bfloat16* __restrict__ xb,
                                                   __hip_bfloat16* __restrict__ Wc) {
    const int tid = threadIdx.x;

    if (blockIdx.x >= 64) {
        // ---- pack x -> bf16 (8192 blocks x 256 thr x 8 elems = 16M elems) ----
        const size_t c = (size_t)(blockIdx.x - 64) * 256 + tid;
        const float* src = x + c * 8;
        floatx4 v0 = *(const floatx4*)(src);
        floatx4 v1 = *(const floatx4*)(src + 4);
        union { short8 s; __hip_bfloat16 h[8]; } u;
#pragma unroll
        for (int i = 0; i < 4; ++i) {
            u.h[i]     = __float2bfloat16(v0[i]);
            u.h[4 + i] = __float2bfloat16(v1[i]);
        }
        *(short8*)(xb + c * 8) = u.s;
        return;
    }

    // ---- Wc GEMM block ----
    __shared__ __hip_bfloat16 As[128 * 64];   // [row j][s-slice]
    __shared__ __hip_bfloat16 Bs2[64 * 128];  // [s-slice][col k]

    const int wave = tid >> 6, lane = tid & 63;
    const int quad = lane >> 4, l16 = lane & 15;
    const int wm = wave & 1, wn = wave >> 1;
    const int bw = blockIdx.x;                 // 0..63 -> 8x8 tile grid
    const int m0 = (bw >> 3) * 128;            // j rows of Wc (rows of Wi)
    const int n0 = (bw & 7) * 128;             // k cols of Wc

    floatx4 acc[4][4];
#pragma unroll
    for (int i = 0; i < 4; ++i)
#pragma unroll
        for (int j = 0; j < 4; ++j) acc[i][j] = {0.f, 0.f, 0.f, 0.f};

    for (int k0 = 0; k0 < 256; k0 += 64) {
        // stage A: Wi rows m0..m0+127, s-slice [k0,k0+64)
#pragma unroll
        for (int i = 0; i < 4; ++i) {
            const int c = i * 256 + tid;       // r = c>>3, k8 = (c&7)*8
            const float* s = w_init + (size_t)(m0 + (c >> 3)) * 256 + k0 + (c & 7) * 8;
            floatx4 v0 = *(const floatx4*)(s);
            floatx4 v1 = *(const floatx4*)(s + 4);
            union { short8 sv; __hip_bfloat16 h[8]; } u;
#pragma unroll
            for (int q = 0; q < 4; ++q) {
                u.h[q]     = __float2bfloat16(v0[q]);
                u.h[4 + q] = __float2bfloat16(v1[q]);
            }
            *(short8*)&As[c * 8] = u.sv;
        }
        // stage B: Ws rows s=k0+ss, cols n0..n0+127 -> Bs2[ss][col]
#pragma unroll
        for (int i = 0; i < 4; ++i) {
            const int fc = i * 256 + tid;      // ss = fc>>4, c8 = (fc&15)*8
            const float* s = w_sample + (size_t)(k0 + (fc >> 4)) * 1024 + n0 + (fc & 15) * 8;
            floatx4 v0 = *(const floatx4*)(s);
            floatx4 v1 = *(const floatx4*)(s + 4);
            union { short8 sv; __hip_bfloat16 h[8]; } u;
#pragma unroll
            for (int q = 0; q < 4; ++q) {
                u.h[q]     = __float2bfloat16(v0[q]);
                u.h[4 + q] = __float2bfloat16(v1[q]);
            }
            *(short8*)&Bs2[(fc >> 4) * 128 + (fc & 15) * 8] = u.sv;
        }
        __syncthreads();

#pragma unroll
        for (int kk = 0; kk < 2; ++kk) {
            short8 af[4], bfr[4];
#pragma unroll
            for (int i = 0; i < 4; ++i)
                af[i] = *(const short8*)&As[(wm * 64 + i * 16 + l16) * 64 + kk * 32 + quad * 8];
#pragma unroll
            for (int j = 0; j < 4; ++j) {
                const int col = wn * 64 + j * 16 + l16;
#pragma unroll
                for (int jj = 0; jj < 8; ++jj)
                    bfr[j][jj] = *(const short*)&Bs2[(kk * 32 + quad * 8 + jj) * 128 + col];
            }
#pragma unroll
            for (int i = 0; i < 4; ++i)
#pragma unroll
                for (int j = 0; j < 4; ++j)
                    acc[i][j] = __builtin_amdgcn_mfma_f32_16x16x32_bf16(af[i], bfr[j], acc[i][j], 0, 0, 0);
        }
        __syncthreads();
    }

    // epilogue: Wc[row(j), col(k)] bf16
#pragma unroll
    for (int i = 0; i < 4; ++i)
#pragma unroll
        for (int r = 0; r < 4; ++r) {
            const int row = m0 + wm * 64 + i * 16 + quad * 4 + r;
#pragma unroll
            for (int j = 0; j < 4; ++j) {
                const int col = n0 + wn * 64 + j * 16 + l16;
                Wc[(size_t)row * 1024 + col] = __float2bfloat16(acc[i][j][r]);
            }
        }
}

// ---------------------------------------------------------------------------
// Stage 2 (main): y = fold( unfold(xb) @ Wc^T ), fp32 out.
// M=16384, N=1024, K=1024. BM=BN=128, BK=64, grid 1024, 256 thr (2x2 waves).
// m97 structure: global_load_lds width-16 staging; A addresses follow the
// unfold mapping (per-lane gather is legal; LDS dest stays wave-uniform +
// lane*16); per-thread A pointers advance by a constant 2048 elems per iter.
// Epilogue folds rec[p, kh*32+kw] -> y[b, nh*32+kh, nw*32+kw].
// ---------------------------------------------------------------------------
__global__ __launch_bounds__(256) void main_gemm(const __hip_bfloat16* __restrict__ xb,
                                                 const __hip_bfloat16* __restrict__ Wc,
                                                 float* __restrict__ Y) {
    __shared__ __hip_bfloat16 As[128 * 64];
    __shared__ __hip_bfloat16 Bs[128 * 64];

    const int tid  = threadIdx.x;
    const int wave = tid >> 6, lane = tid & 63;
    const int quad = lane >> 4, l16 = lane & 15;
    const int wm = wave & 1, wn = wave >> 1;

    const int bm = blockIdx.x >> 3;            // 0..127
    const int bn = blockIdx.x & 7;             // 0..7
    const int m0 = bm * 128;                   // patch base
    const int n0 = bn * 128;                   // output-k base

    // per-thread A source pointers (unfold mapping), advance +2048 elems/iter
    const int tq  = tid >> 3;                  // 0..31 : patch-row group
    const int k8l = (tid & 7) * 8;             // 0..56 : k-octet within BK
    const int khl = k8l >> 5, kwl = k8l & 31;
    const __hip_bfloat16* srcA[4];
#pragma unroll
    for (int i = 0; i < 4; ++i) {
        const int r  = i * 32 + tq;
        const int p  = m0 + r;
        const int b  = p >> 10, pl = p & 1023;
        const int nh = pl >> 5, nw = pl & 31;
        srcA[i] = xb + ((size_t)b << 20) + (size_t)(nh * 32 + khl) * 1024 + nw * 32 + kwl;
    }
    // B source pointers: Wc rows n0+(c>>3), k-octet (c&7)*8 ; advance +64/iter
    const __hip_bfloat16* srcB[4];
#pragma unroll
    for (int i = 0; i < 4; ++i) {
        const int c = i * 256 + tid;
        srcB[i] = Wc + (size_t)(n0 + (c >> 3)) * 1024 + (c & 7) * 8;
    }

    floatx4 acc[4][4];
#pragma unroll
    for (int i = 0; i < 4; ++i)
#pragma unroll
        for (int j = 0; j < 4; ++j) acc[i][j] = {0.f, 0.f, 0.f, 0.f};

    for (int it = 0; it < 16; ++it) {
#pragma unroll
        for (int i = 0; i < 4; ++i) {
            __builtin_amdgcn_global_load_lds(GPTR(srcA[i]), LPTR(&As[i * 2048 + tid * 8]), 16, 0, 0);
            srcA[i] += 2048;
        }
#pragma unroll
        for (int i = 0; i < 4; ++i) {
            __builtin_amdgcn_global_load_lds(GPTR(srcB[i]), LPTR(&Bs[i * 2048 + tid * 8]), 16, 0, 0);
            srcB[i] += 64;
        }
        __syncthreads();

#pragma unroll
        for (int kk = 0; kk < 2; ++kk) {
            short8 af[4], bfr[4];
#pragma unroll
            for (int i = 0; i < 4; ++i)
                af[i] = *(const short8*)&As[(wm * 64 + i * 16 + l16) * 64 + kk * 32 + quad * 8];
#pragma unroll
            for (int j = 0; j < 4; ++j)
                bfr[j] = *(const short8*)&Bs[(wn * 64 + j * 16 + l16) * 64 + kk * 32 + quad * 8];
#pragma unroll
            for (int i = 0; i < 4; ++i)
#pragma unroll
                for (int j = 0; j < 4; ++j)
                    acc[i][j] = __builtin_amdgcn_mfma_f32_16x16x32_bf16(af[i], bfr[j], acc[i][j], 0, 0, 0);
        }
        __syncthreads();
    }

    // fold epilogue
#pragma unroll
    for (int i = 0; i < 4; ++i)
#pragma unroll
        for (int r = 0; r < 4; ++r) {
            const int row = m0 + wm * 64 + i * 16 + quad * 4 + r;   // patch idx
            const int b  = row >> 10, pl = row & 1023;
            const int nh = pl >> 5,  nw = pl & 31;
            const size_t base = ((size_t)b << 20) + (size_t)nh * 32768 + (size_t)nw * 32;
#pragma unroll
            for (int j = 0; j < 4; ++j) {
                const int col = n0 + wn * 64 + j * 16 + l16;        // kh*32+kw
                const int kh = col >> 5, kw = col & 31;
                Y[base + (size_t)kh * 1024 + kw] = acc[i][j][r];
            }
        }
}

// ---------------------------------------------------------------------------
// Workspace: xb bf16 [16*1024*1024] @ 0 (33554432 B); Wc bf16 [1024*1024]
// @ 33554432 (2097152 B). Total ~35.7 MB.
// ---------------------------------------------------------------------------
extern "C" void kernel_launch(void* const* d_in, const int* in_sizes, int n_in,
                              void* d_out, int out_size, void* d_ws, size_t ws_size,
                              hipStream_t stream) {
    const float* x        = (const float*)d_in[0];
    const float* w_sample = (const float*)d_in[1];
    const float* w_init   = (const float*)d_in[2];
    float* y = (float*)d_out;
    char* ws = (char*)d_ws;

    __hip_bfloat16* xb = (__hip_bfloat16*)(ws);
    __hip_bfloat16* Wc = (__hip_bfloat16*)(ws + (size_t)33554432);

    prep_kernel<<<64 + 8192, 256, 0, stream>>>(x, w_sample, w_init, xb, Wc);
    main_gemm<<<1024, 256, 0, stream>>>(xb, Wc, y);
}

// Round 3
// 158.008 us; speedup vs baseline: 1.0694x; 1.0694x over previous
//
#include <hip/hip_runtime.h>
#include <hip/hip_bf16.h>

using short8  = __attribute__((ext_vector_type(8))) short;
using floatx4 = __attribute__((ext_vector_type(4))) float;

#define GPTR(p) ((const __attribute__((address_space(1))) void*)(p))
#define LPTR(p) ((__attribute__((address_space(3))) void*)(p))

// ---------------------------------------------------------------------------
// pack_w: both weight matrices fp32 -> bf16 (native layouts are already the
// B^T form each GEMM needs). w_sample [256,1024] -> wsb ; w_init [1024,256]
// -> wib. 262144 elems each = 32768 16B-chunks each.
// ---------------------------------------------------------------------------
__global__ __launch_bounds__(256) void pack_w_kernel(const float* __restrict__ w_sample,
                                                     const float* __restrict__ w_init,
                                                     __hip_bfloat16* __restrict__ wsb,
                                                     __hip_bfloat16* __restrict__ wib) {
    const int c = blockIdx.x * 256 + threadIdx.x;     // 0 .. 65535
    const float* src;
    __hip_bfloat16* dst;
    if (c < 32768) { src = w_sample + (size_t)c * 8;           dst = wsb + (size_t)c * 8; }
    else           { src = w_init   + (size_t)(c - 32768) * 8; dst = wib + (size_t)(c - 32768) * 8; }
    floatx4 v0 = *(const floatx4*)(src);
    floatx4 v1 = *(const floatx4*)(src + 4);
    union { short8 s; __hip_bfloat16 h[8]; } u;
#pragma unroll
    for (int i = 0; i < 4; ++i) {
        u.h[i]     = __float2bfloat16(v0[i]);
        u.h[4 + i] = __float2bfloat16(v1[i]);
    }
    *(short8*)(dst) = u.s;
}

// ---------------------------------------------------------------------------
// GEMM1: meas[16384,256] = unfold(x) @ Ws^T.  M=16384, N=256, K=1024.
// 512 threads = 8 waves (wm in {0,1} x wn in {0..3}); BM=128, BN=128,
// grid 256 (128 m-tiles x 2 n-tiles), BK=64, 16 K-iters.
// A is staged straight from x fp32: unfold gather (2 rows of 64B per thread
// -> 4 dwordx4), cvt to bf16, ds_write into As padded to 72 elems/row
// (stride 144 B -> frag reads conflict-free). B (wsb, bf16) via
// global_load_lds width 16 (unpadded 64/row -> known-ok 2x b128 pattern).
// Per thread: am = tid>>2 (row), akq = (tid&3)*16 (k-quad); k0 advance of 64
// = +2 image rows = +8192 B constant stride.
// ---------------------------------------------------------------------------
__global__ __launch_bounds__(512) void gemm1_kernel(const float* __restrict__ x,
                                                    const __hip_bfloat16* __restrict__ wsb,
                                                    __hip_bfloat16* __restrict__ meas) {
    __shared__ __hip_bfloat16 As[128 * 72];
    __shared__ __hip_bfloat16 Bs[128 * 64];

    const int tid  = threadIdx.x;
    const int wave = tid >> 6, lane = tid & 63;
    const int quad = lane >> 4, l16 = lane & 15;
    const int wm = wave & 1, wn = wave >> 1;            // WM=64, WN=32

    const int bm = blockIdx.x >> 1;                      // 0..127
    const int bn = blockIdx.x & 1;                       // 0..1
    const int m0 = bm * 128, n0 = bn * 128;

    // A source: thread -> (row am, k-offset akq), 16 consecutive k (one kh row)
    const int am  = tid >> 2;                            // 0..127
    const int akq = (tid & 3) * 16;                      // 0,16,32,48
    {
    }
    const int p  = m0 + am;
    const int pb = p >> 10, pl = p & 1023;
    const int nh = pl >> 5, nw = pl & 31;
    const int kh0 = akq >> 5, kw0 = akq & 31;            // (0,0)(0,16)(1,0)(1,16)
    const float* srcA = x + ((size_t)pb << 20) + (size_t)(nh * 32 + kh0) * 1024 + nw * 32 + kw0;
    __hip_bfloat16* dstA = &As[am * 72 + akq];

    // B source: chunk c = i*512+tid -> s-row c>>3, k-octet (c&7)*8
    const __hip_bfloat16* srcB[2];
#pragma unroll
    for (int i = 0; i < 2; ++i) {
        const int c = i * 512 + tid;
        srcB[i] = wsb + (size_t)(n0 + (c >> 3)) * 1024 + (c & 7) * 8;
    }

    floatx4 acc[4][2];
#pragma unroll
    for (int i = 0; i < 4; ++i)
#pragma unroll
        for (int j = 0; j < 2; ++j) acc[i][j] = {0.f, 0.f, 0.f, 0.f};

    for (int it = 0; it < 16; ++it) {
        floatx4 va0 = *(const floatx4*)(srcA);
        floatx4 va1 = *(const floatx4*)(srcA + 4);
        floatx4 va2 = *(const floatx4*)(srcA + 8);
        floatx4 va3 = *(const floatx4*)(srcA + 12);
        srcA += 2048;                                    // +64 k = +2 image rows
#pragma unroll
        for (int i = 0; i < 2; ++i) {
            __builtin_amdgcn_global_load_lds(GPTR(srcB[i]), LPTR(&Bs[(i * 512 + tid) * 8]), 16, 0, 0);
            srcB[i] += 64;
        }
        union { short8 s; __hip_bfloat16 h[8]; } u0, u1;
#pragma unroll
        for (int q = 0; q < 4; ++q) {
            u0.h[q]     = __float2bfloat16(va0[q]);
            u0.h[4 + q] = __float2bfloat16(va1[q]);
            u1.h[q]     = __float2bfloat16(va2[q]);
            u1.h[4 + q] = __float2bfloat16(va3[q]);
        }
        *(short8*)(dstA)     = u0.s;
        *(short8*)(dstA + 8) = u1.s;
        __syncthreads();

#pragma unroll
        for (int kk = 0; kk < 2; ++kk) {
            short8 af[4], bfr[2];
#pragma unroll
            for (int i = 0; i < 4; ++i)
                af[i] = *(const short8*)&As[(wm * 64 + i * 16 + l16) * 72 + kk * 32 + quad * 8];
#pragma unroll
            for (int j = 0; j < 2; ++j)
                bfr[j] = *(const short8*)&Bs[(wn * 32 + j * 16 + l16) * 64 + kk * 32 + quad * 8];
#pragma unroll
            for (int i = 0; i < 4; ++i)
#pragma unroll
                for (int j = 0; j < 2; ++j)
                    acc[i][j] = __builtin_amdgcn_mfma_f32_16x16x32_bf16(af[i], bfr[j], acc[i][j], 0, 0, 0);
        }
        __syncthreads();
    }

    // epilogue: meas[p, s] bf16 (C/D: col=l16, row=quad*4+r — verified)
#pragma unroll
    for (int i = 0; i < 4; ++i)
#pragma unroll
        for (int r = 0; r < 4; ++r) {
            const int row = m0 + wm * 64 + i * 16 + quad * 4 + r;
#pragma unroll
            for (int j = 0; j < 2; ++j) {
                const int col = n0 + wn * 32 + j * 16 + l16;
                meas[(size_t)row * 256 + col] = __float2bfloat16(acc[i][j][r]);
            }
        }
}

// ---------------------------------------------------------------------------
// GEMM2: y = fold( meas[16384,256] @ Wi^T ).  M=16384, N=1024, K=256.
// R2 main_gemm structure verbatim (verified): 256 thr, BM=BN=128, grid 1024,
// 4 K-iters, A=meas bf16 + B=wib bf16 both via global_load_lds, fold epilogue.
// ---------------------------------------------------------------------------
__global__ __launch_bounds__(256) void gemm2_kernel(const __hip_bfloat16* __restrict__ meas,
                                                    const __hip_bfloat16* __restrict__ wib,
                                                    float* __restrict__ Y) {
    __shared__ __hip_bfloat16 As[128 * 64];
    __shared__ __hip_bfloat16 Bs[128 * 64];

    const int tid  = threadIdx.x;
    const int wave = tid >> 6, lane = tid & 63;
    const int quad = lane >> 4, l16 = lane & 15;
    const int wm = wave & 1, wn = wave >> 1;

    const int bm = blockIdx.x >> 3;            // 0..127 (m-major: B reuse in L2)
    const int bn = blockIdx.x & 7;             // 0..7
    const int m0 = bm * 128, n0 = bn * 128;

    const __hip_bfloat16* srcA[4];
    const __hip_bfloat16* srcB[4];
#pragma unroll
    for (int i = 0; i < 4; ++i) {
        const int c = i * 256 + tid;
        srcA[i] = meas + (size_t)(m0 + (c >> 3)) * 256 + (c & 7) * 8;
        srcB[i] = wib  + (size_t)(n0 + (c >> 3)) * 256 + (c & 7) * 8;
    }

    floatx4 acc[4][4];
#pragma unroll
    for (int i = 0; i < 4; ++i)
#pragma unroll
        for (int j = 0; j < 4; ++j) acc[i][j] = {0.f, 0.f, 0.f, 0.f};

    for (int it = 0; it < 4; ++it) {
#pragma unroll
        for (int i = 0; i < 4; ++i) {
            __builtin_amdgcn_global_load_lds(GPTR(srcA[i]), LPTR(&As[i * 2048 + tid * 8]), 16, 0, 0);
            srcA[i] += 64;
        }
#pragma unroll
        for (int i = 0; i < 4; ++i) {
            __builtin_amdgcn_global_load_lds(GPTR(srcB[i]), LPTR(&Bs[i * 2048 + tid * 8]), 16, 0, 0);
            srcB[i] += 64;
        }
        __syncthreads();

#pragma unroll
        for (int kk = 0; kk < 2; ++kk) {
            short8 af[4], bfr[4];
#pragma unroll
            for (int i = 0; i < 4; ++i)
                af[i] = *(const short8*)&As[(wm * 64 + i * 16 + l16) * 64 + kk * 32 + quad * 8];
#pragma unroll
            for (int j = 0; j < 4; ++j)
                bfr[j] = *(const short8*)&Bs[(wn * 64 + j * 16 + l16) * 64 + kk * 32 + quad * 8];
#pragma unroll
            for (int i = 0; i < 4; ++i)
#pragma unroll
                for (int j = 0; j < 4; ++j)
                    acc[i][j] = __builtin_amdgcn_mfma_f32_16x16x32_bf16(af[i], bfr[j], acc[i][j], 0, 0, 0);
        }
        __syncthreads();
    }

    // fold epilogue (verified in R2): row=p -> (b,nh,nw); col=k' -> (kh,kw)
#pragma unroll
    for (int i = 0; i < 4; ++i)
#pragma unroll
        for (int r = 0; r < 4; ++r) {
            const int row = m0 + wm * 64 + i * 16 + quad * 4 + r;
            const int b  = row >> 10, pl = row & 1023;
            const int nh = pl >> 5,  nw = pl & 31;
            const size_t base = ((size_t)b << 20) + (size_t)nh * 32768 + (size_t)nw * 32;
#pragma unroll
            for (int j = 0; j < 4; ++j) {
                const int col = n0 + wn * 64 + j * 16 + l16;
                const int kh = col >> 5, kw = col & 31;
                Y[base + (size_t)kh * 1024 + kw] = acc[i][j][r];
            }
        }
}

// ---------------------------------------------------------------------------
// Workspace: meas bf16 [16384*256] @ 0 (8388608 B); wsb bf16 [256*1024]
// @ 8388608 (524288 B); wib bf16 [1024*256] @ 8912896 (524288 B). ~9.4 MB.
// ---------------------------------------------------------------------------
extern "C" void kernel_launch(void* const* d_in, const int* in_sizes, int n_in,
                              void* d_out, int out_size, void* d_ws, size_t ws_size,
                              hipStream_t stream) {
    const float* x        = (const float*)d_in[0];
    const float* w_sample = (const float*)d_in[1];
    const float* w_init   = (const float*)d_in[2];
    float* y = (float*)d_out;
    char* ws = (char*)d_ws;

    __hip_bfloat16* meas = (__hip_bfloat16*)(ws);
    __hip_bfloat16* wsb  = (__hip_bfloat16*)(ws + (size_t)8388608);
    __hip_bfloat16* wib  = (__hip_bfloat16*)(ws + (size_t)8912896);

    pack_w_kernel<<<256, 256, 0, stream>>>(w_sample, w_init, wsb, wib);
    gemm1_kernel<<<256, 512, 0, stream>>>(x, wsb, meas);
    gemm2_kernel<<<1024, 256, 0, stream>>>(meas, wib, y);
}

// Round 4
// 136.070 us; speedup vs baseline: 1.2418x; 1.1612x over previous
//
#include <hip/hip_runtime.h>
#include <hip/hip_bf16.h>

using short8  = __attribute__((ext_vector_type(8))) short;
using floatx4 = __attribute__((ext_vector_type(4))) float;

// ---------------------------------------------------------------------------
// prepack: weights fp32 -> bf16 in MFMA-B-fragment-tiled layout.
// Fragment (nblk, kstep) occupies 64 lanes x 8 elems contiguous; lane l holds
// B[n = nblk*16 + (l&15)][k = kstep*32 + (l>>4)*8 .. +7]  (verified B-frag
// mapping: row=lane&15, k=quad*8+j). Loading a frag = one coalesced 1-KiB
// global_load_dwordx4 per wave.
//  wsb_t: from w_sample [256 s][1024 k]  -> 16 nblk x 32 kstep   (262144 elems)
//  wib_t: from w_init  [1024 k'][256 s]  -> 64 nblk x  8 kstep   (262144 elems)
// ---------------------------------------------------------------------------
__global__ __launch_bounds__(256) void prepack_kernel(const float* __restrict__ w_sample,
                                                      const float* __restrict__ w_init,
                                                      __hip_bfloat16* __restrict__ wsb_t,
                                                      __hip_bfloat16* __restrict__ wib_t) {
    const int tg   = blockIdx.x * 256 + threadIdx.x;   // 0..65535
    const int lane = tg & 63;
    const int l16  = lane & 15, quad = lane >> 4;
    const float* src;
    __hip_bfloat16* dst;
    if (tg < 32768) {
        const int chunk = tg >> 6;                     // 0..511: nblk=chunk>>5, kstep=chunk&31
        const int n = (chunk >> 5) * 16 + l16;
        const int k = (chunk & 31) * 32 + quad * 8;
        src = w_sample + (size_t)n * 1024 + k;
        dst = wsb_t + (size_t)tg * 8;
    } else {
        const int t2 = tg - 32768;
        const int chunk = t2 >> 6;                     // 0..511: nblk=chunk>>3, kstep=chunk&7
        const int n = (chunk >> 3) * 16 + l16;
        const int k = (chunk & 7) * 32 + quad * 8;
        src = w_init + (size_t)n * 256 + k;
        dst = wib_t + (size_t)t2 * 8;
    }
    floatx4 v0 = *(const floatx4*)(src);
    floatx4 v1 = *(const floatx4*)(src + 4);
    union { short8 s; __hip_bfloat16 h[8]; } u;
#pragma unroll
    for (int i = 0; i < 4; ++i) {
        u.h[i]     = __float2bfloat16(v0[i]);
        u.h[4 + i] = __float2bfloat16(v1[i]);
    }
    *(short8*)dst = u.s;
}

// ---------------------------------------------------------------------------
// fused: per block = 32 patches sharing (b, nh) => one contiguous 32-row
// image slab x[blk*32768 .. +32767].
//  Phase 1: meas[32x256] = patch[32x1024] @ Ws^T  (K=1024, 16 iters BK=64)
//    - As [32][64] bf16 ping-pong in LDS (4 KB x2), cvt from fp32 inline,
//      ONE barrier per iter; B-frags register-direct from wsb_t (L2).
//    - 4 waves split N=256 into 64-col ranges; wave tile 32x64 (MI=2,NI=4).
//  meas -> LDS [32][264] (pad 8: A-frag b128 reads ~2-way = free).
//  Phase 2 (barrier-free): rec[32x1024] = meas @ Wi^T (K=256), 4 n-chunks of
//    256; A-frags from Ms, B-frags register-direct from wib_t (L2);
//    fold-epilogue per chunk straight to y fp32.
// Verified layouts used throughout: A/B frag row=lane&15, k=quad*8+j;
// C/D col=lane&15, row=quad*4+reg.
// ---------------------------------------------------------------------------
__global__ __launch_bounds__(256, 2) void fused_kernel(const float* __restrict__ x,
                                                       const __hip_bfloat16* __restrict__ wsb_t,
                                                       const __hip_bfloat16* __restrict__ wib_t,
                                                       float* __restrict__ Y) {
    __shared__ __hip_bfloat16 As[2][2048];     // ping-pong A tile [32][64]
    __shared__ __hip_bfloat16 Ms[32 * 264];    // meas tile, row stride 264

    const int tid  = threadIdx.x;
    const int wave = tid >> 6, lane = tid & 63;
    const int quad = lane >> 4, l16 = lane & 15;
    const int blk  = blockIdx.x;               // blk = b*32 + nh

    // A staging: thread -> (nw = tid>>3, 8 consecutive k at k8=(tid&7)*8)
    const float* srcX = x + (size_t)blk * 32768
                        + ((tid & 7) >> 2) * 1024 + (tid >> 3) * 32 + (tid & 3) * 8;

    // register-direct B-frag bases (each wave reads its private quarter)
    const __hip_bfloat16* baseW1 = wsb_t + (size_t)wave * 65536 + lane * 8;
    const __hip_bfloat16* baseW2 = wib_t + (size_t)wave * 16384 + lane * 8;

    floatx4 acc[2][4];
#pragma unroll
    for (int i = 0; i < 2; ++i)
#pragma unroll
        for (int j = 0; j < 4; ++j) acc[i][j] = {0.f, 0.f, 0.f, 0.f};

    // ---------------- phase 1 ----------------
    floatx4 v0 = *(const floatx4*)(srcX);
    floatx4 v1 = *(const floatx4*)(srcX + 4);
    srcX += 2048;

    for (int it = 0; it < 16; ++it) {
        union { short8 s; __hip_bfloat16 h[8]; } u;
#pragma unroll
        for (int q = 0; q < 4; ++q) {
            u.h[q]     = __float2bfloat16(v0[q]);
            u.h[4 + q] = __float2bfloat16(v1[q]);
        }
        *(short8*)&As[it & 1][tid * 8] = u.s;
        __syncthreads();                        // write(it) visible; prev reads done
        if (it < 15) {                          // prefetch next slab rows (latency
            v0 = *(const floatx4*)(srcX);       //  hides under the MFMA below)
            v1 = *(const floatx4*)(srcX + 4);
            srcX += 2048;
        }
        const __hip_bfloat16* Ap = As[it & 1];
#pragma unroll
        for (int kk = 0; kk < 2; ++kk) {
            short8 af[2], bfr[4];
#pragma unroll
            for (int i = 0; i < 2; ++i)
                af[i] = *(const short8*)&Ap[(i * 16 + l16) * 64 + kk * 32 + quad * 8];
#pragma unroll
            for (int j = 0; j < 4; ++j)
                bfr[j] = *(const short8*)(baseW1 + (size_t)(j * 32 + it * 2 + kk) * 512);
#pragma unroll
            for (int i = 0; i < 2; ++i)
#pragma unroll
                for (int j = 0; j < 4; ++j)
                    acc[i][j] = __builtin_amdgcn_mfma_f32_16x16x32_bf16(af[i], bfr[j], acc[i][j], 0, 0, 0);
        }
    }

    // meas (C-layout) -> Ms row-major [m][s]
#pragma unroll
    for (int i = 0; i < 2; ++i)
#pragma unroll
        for (int r = 0; r < 4; ++r) {
            const int row = i * 16 + quad * 4 + r;
#pragma unroll
            for (int j = 0; j < 4; ++j)
                Ms[row * 264 + wave * 64 + j * 16 + l16] = __float2bfloat16(acc[i][j][r]);
        }
    __syncthreads();

    // ---------------- phase 2 (barrier-free) ----------------
    float* ybase = Y + (size_t)blk * 32768;
#pragma unroll 1
    for (int c = 0; c < 4; ++c) {
        floatx4 a2[2][4];
#pragma unroll
        for (int i = 0; i < 2; ++i)
#pragma unroll
            for (int j = 0; j < 4; ++j) a2[i][j] = {0.f, 0.f, 0.f, 0.f};
        const __hip_bfloat16* w2 = baseW2 + (size_t)c * 65536;
#pragma unroll
        for (int ks = 0; ks < 8; ++ks) {
            short8 af[2], bfr[4];
#pragma unroll
            for (int i = 0; i < 2; ++i)
                af[i] = *(const short8*)&Ms[(i * 16 + l16) * 264 + ks * 32 + quad * 8];
#pragma unroll
            for (int j = 0; j < 4; ++j)
                bfr[j] = *(const short8*)(w2 + (size_t)j * 4096 + ks * 512);
#pragma unroll
            for (int i = 0; i < 2; ++i)
#pragma unroll
                for (int j = 0; j < 4; ++j)
                    a2[i][j] = __builtin_amdgcn_mfma_f32_16x16x32_bf16(af[i], bfr[j], a2[i][j], 0, 0, 0);
        }
        // fold epilogue: m = nw; col = c*256 + wave*64 + j*16 + l16 -> (kh,kw)
#pragma unroll
        for (int i = 0; i < 2; ++i)
#pragma unroll
            for (int r = 0; r < 4; ++r) {
                const int m = i * 16 + quad * 4 + r;
#pragma unroll
                for (int j = 0; j < 4; ++j) {
                    const int col = c * 256 + wave * 64 + j * 16 + l16;
                    const int kh = col >> 5, kw = col & 31;
                    ybase[kh * 1024 + m * 32 + kw] = a2[i][j][r];
                }
            }
    }
}

// ---------------------------------------------------------------------------
// Workspace: wsb_t bf16 [262144] @ 0 (524288 B); wib_t bf16 [262144]
// @ 524288 (524288 B). Total 1 MB.
// ---------------------------------------------------------------------------
extern "C" void kernel_launch(void* const* d_in, const int* in_sizes, int n_in,
                              void* d_out, int out_size, void* d_ws, size_t ws_size,
                              hipStream_t stream) {
    const float* x        = (const float*)d_in[0];
    const float* w_sample = (const float*)d_in[1];
    const float* w_init   = (const float*)d_in[2];
    float* y = (float*)d_out;
    char* ws = (char*)d_ws;

    __hip_bfloat16* wsb_t = (__hip_bfloat16*)(ws);
    __hip_bfloat16* wib_t = (__hip_bfloat16*)(ws + (size_t)524288);

    prepack_kernel<<<256, 256, 0, stream>>>(w_sample, w_init, wsb_t, wib_t);
    fused_kernel<<<512, 256, 0, stream>>>(x, wsb_t, wib_t, y);
}